// Round 3
// baseline (256.612 us; speedup 1.0000x reference)
//
#include <hip/hip_runtime.h>
#include <hip/hip_bf16.h>

// B=8, T=2048, D=1024, HS=128 causal attention head.
// wprep (W->Wt bf16, coalesced) ; qkv_gemm (m97-style, global_load_lds, V transposed)
// attn (fixed-base softmax, 4-way key split, 8-wave blocks) ; merge.

typedef __bf16 bf16x8 __attribute__((ext_vector_type(8)));
typedef __bf16 bf16x4 __attribute__((ext_vector_type(4)));
typedef float floatx4 __attribute__((ext_vector_type(4)));

#define B_  8
#define T_  2048
#define D_  1024
#define HS_ 128
#define M_  (B_ * T_)   // 16384

// ws byte offsets (end = 30408704, proven safe in round 2)
#define OFF_Q   0u
#define OFF_K   4194304u
#define OFF_VT  8388608u
#define OFF_WT  12582912u          // 3*128*1024*2 = 786432
#define OFF_OP  13369344u          // 4 splits * 16384*128*2 (bf16) = 16777216
#define OFF_LP  30146560u          // 4 * 16384 * 4 = 262144

// async global->LDS, 16B per lane; LDS dest = wave-uniform base + lane*16
#define GLL16(gp, lp) __builtin_amdgcn_global_load_lds( \
    (const __attribute__((address_space(1))) void*)(gp), \
    (__attribute__((address_space(3))) void*)(lp), 16, 0, 0)

// ---------------------------------------------------------------------------
// W[1024,128] fp32 -> Wt[128,1024] bf16 (x3), coalesced via LDS transpose.
// grid (16, 3): 64-k x 128-n tile per block.
// ---------------------------------------------------------------------------
__global__ __launch_bounds__(256) void wprep(
    const float* __restrict__ Wq, const float* __restrict__ Wk,
    const float* __restrict__ Wv, __hip_bfloat16* __restrict__ Wt)
{
    __shared__ __hip_bfloat16 sT[128][80];   // [n][k], 160B rows keep b128 aligned
    const int wsel = blockIdx.y;
    const int k0   = blockIdx.x * 64;
    const float* W = (wsel == 0) ? Wq : ((wsel == 1) ? Wk : Wv);

    #pragma unroll
    for (int i = 0; i < 8; ++i) {
        const int idx = threadIdx.x + i * 256;   // 2048 float4s
        const int kr  = idx >> 5;                // 0..63
        const int f4  = idx & 31;                // float4 along n
        const float4 v = *(const float4*)(W + (size_t)(k0 + kr) * HS_ + f4 * 4);
        sT[f4 * 4 + 0][kr] = __float2bfloat16(v.x);
        sT[f4 * 4 + 1][kr] = __float2bfloat16(v.y);
        sT[f4 * 4 + 2][kr] = __float2bfloat16(v.z);
        sT[f4 * 4 + 3][kr] = __float2bfloat16(v.w);
    }
    __syncthreads();
    #pragma unroll
    for (int i = 0; i < 4; ++i) {
        const int idx = threadIdx.x + i * 256;   // 128 n x 8 segs
        const int n   = idx >> 3;
        const int sg  = idx & 7;
        *(bf16x8*)(Wt + (size_t)wsel * HS_ * D_ + (size_t)n * D_ + k0 + sg * 8) =
            *(const bf16x8*)&sT[n][sg * 8];
    }
}

// ---------------------------------------------------------------------------
// QKV GEMM, m97-style. C[16384,128] = bf16(x)*Wt^T. Tile 128x128, BK=64.
// A staged as fp32 via global_load_lds, converted at fragment read.
// grid (128, 3), 256 threads. V written transposed [b][hs][t].
// ---------------------------------------------------------------------------
__global__ __launch_bounds__(256, 3) void qkv_gemm(
    const float* __restrict__ x, const __hip_bfloat16* __restrict__ Wt_all,
    __hip_bfloat16* __restrict__ qg, __hip_bfloat16* __restrict__ kg,
    __hip_bfloat16* __restrict__ vtg)
{
    __shared__ float sA[128][64];            // 32 KB, unpadded (global_load_lds)
    __shared__ __hip_bfloat16 sB[128][64];   // 16 KB

    const int mt   = blockIdx.x;
    const int wsel = blockIdx.y;
    const __hip_bfloat16* Wt = Wt_all + (size_t)wsel * HS_ * D_;

    const int tid  = threadIdx.x;
    const int lane = tid & 63;
    const int w    = tid >> 6;
    const int quad = lane >> 4;
    const int l16  = lane & 15;
    const int wrow = (w & 1) * 64;
    const int wcol = (w >> 1) * 64;
    const int m0   = mt * 128;

    const int ar = lane >> 4, as = lane & 15;   // A: 4 rows/issue, 16B=4 floats
    const int br = lane >> 3, bs = lane & 7;    // B: 8 rows/issue, 16B=8 bf16

    floatx4 acc[4][4];
    #pragma unroll
    for (int i = 0; i < 4; ++i)
        #pragma unroll
        for (int j = 0; j < 4; ++j) acc[i][j] = (floatx4){0.f, 0.f, 0.f, 0.f};

    for (int kt = 0; kt < D_ / 64; ++kt) {
        const int k0 = kt * 64;
        #pragma unroll
        for (int i = 0; i < 8; ++i) {   // A rows w*32 .. w*32+31
            const int rb = w * 32 + i * 4;
            GLL16(x + (size_t)(m0 + rb + ar) * D_ + k0 + as * 4, &sA[rb][0]);
        }
        #pragma unroll
        for (int i = 0; i < 4; ++i) {   // B rows w*32 .. w*32+31
            const int rb = w * 32 + i * 8;
            GLL16(Wt + (size_t)(rb + br) * D_ + k0 + bs * 8, &sB[rb][0]);
        }
        __syncthreads();

        #pragma unroll
        for (int ks = 0; ks < 2; ++ks) {
            bf16x8 af[4], bfr[4];
            #pragma unroll
            for (int i = 0; i < 4; ++i) {
                const float* ap = &sA[wrow + i * 16 + l16][ks * 32 + quad * 8];
                const float4 f0 = *(const float4*)ap;
                const float4 f1 = *(const float4*)(ap + 4);
                union { bf16x8 v; __hip_bfloat16 h[8]; } u;
                u.h[0] = __float2bfloat16(f0.x); u.h[1] = __float2bfloat16(f0.y);
                u.h[2] = __float2bfloat16(f0.z); u.h[3] = __float2bfloat16(f0.w);
                u.h[4] = __float2bfloat16(f1.x); u.h[5] = __float2bfloat16(f1.y);
                u.h[6] = __float2bfloat16(f1.z); u.h[7] = __float2bfloat16(f1.w);
                af[i] = u.v;
            }
            #pragma unroll
            for (int j = 0; j < 4; ++j)
                bfr[j] = *(const bf16x8*)&sB[wcol + j * 16 + l16][ks * 32 + quad * 8];
            #pragma unroll
            for (int i = 0; i < 4; ++i)
                #pragma unroll
                for (int j = 0; j < 4; ++j)
                    acc[i][j] = __builtin_amdgcn_mfma_f32_16x16x32_bf16(af[i], bfr[j], acc[i][j], 0, 0, 0);
        }
        __syncthreads();
    }

    if (wsel < 2) {
        __hip_bfloat16* out = wsel ? kg : qg;
        #pragma unroll
        for (int i = 0; i < 4; ++i)
            #pragma unroll
            for (int j = 0; j < 4; ++j)
                #pragma unroll
                for (int r = 0; r < 4; ++r)
                    out[(size_t)(m0 + wrow + i * 16 + quad * 4 + r) * HS_ + wcol + j * 16 + l16] =
                        __float2bfloat16(acc[i][j][r]);
    } else {
        #pragma unroll
        for (int i = 0; i < 4; ++i) {
            const int row0 = m0 + wrow + i * 16 + quad * 4;
            const int bb = row0 >> 11;
            const int t  = row0 & 2047;
            #pragma unroll
            for (int j = 0; j < 4; ++j) {
                const int col = wcol + j * 16 + l16;
                union { bf16x4 v; __hip_bfloat16 h[4]; } u;
                #pragma unroll
                for (int r = 0; r < 4; ++r) u.h[r] = __float2bfloat16(acc[i][j][r]);
                *(bf16x4*)(vtg + (size_t)bb * HS_ * T_ + (size_t)col * T_ + t) = u.v;
            }
        }
    }
}

// ---------------------------------------------------------------------------
// Flash attention, fixed-base softmax (no max tracking / no rescale).
// grid (4 split, 16 qt rev, 8 b), 512 threads = 8 waves, 128 q-rows/block.
// Writes unnormalized O (bf16) + per-row l (fp32) partials.
// ---------------------------------------------------------------------------
__global__ __launch_bounds__(512, 4) void attn(
    const __hip_bfloat16* __restrict__ qg, const __hip_bfloat16* __restrict__ kg,
    const __hip_bfloat16* __restrict__ vtg,
    __hip_bfloat16* __restrict__ Opart, float* __restrict__ lpart)
{
    __shared__ __hip_bfloat16 sK[64][128];    // unpadded (global_load_lds)
    __shared__ __hip_bfloat16 sVt[128][64];   // unpadded
    __shared__ __hip_bfloat16 sP[8][16][72];  // per-wave P buffer (b128-aligned rows)

    const int s  = blockIdx.x;
    const int qt = 15 - blockIdx.y;          // longest first
    const int b  = blockIdx.z;

    const int tid  = threadIdx.x;
    const int lane = tid & 63;
    const int w    = tid >> 6;               // 0..7
    const int quad = lane >> 4;
    const int l16  = lane & 15;

    const int t0 = qt * 128;
    const size_t brow = (size_t)b * T_;
    const __hip_bfloat16* vt_b = vtg + (size_t)b * HS_ * T_;

    const int nt = 2 * qt + 2;               // key tiles of 64
    const int st_begin = (s * nt) >> 2;
    const int st_end   = ((s + 1) * nt) >> 2;

    bf16x8 aq[4];
    #pragma unroll
    for (int kt = 0; kt < 4; ++kt)
        aq[kt] = *(const bf16x8*)(qg + (brow + t0 + w * 16 + l16) * HS_ + kt * 32 + quad * 8);

    floatx4 acc_o[8];
    #pragma unroll
    for (int i = 0; i < 8; ++i) acc_o[i] = (floatx4){0.f, 0.f, 0.f, 0.f};
    float lsum[4] = {0.f, 0.f, 0.f, 0.f};

    const float scale = 0.08838834764831845f;
    const int kr = lane >> 4, ks8 = lane & 15;   // sK: 4 rows/issue x 16 segs
    const int vr = lane >> 3, vs8 = lane & 7;    // sVt: 8 rows/issue x 8 segs

    for (int st = st_begin; st < st_end; ++st) {
        const int s0 = st * 64;
        #pragma unroll
        for (int i = 0; i < 2; ++i) {
            const int kb = w * 8 + i * 4;    // sK rows, 16 issues total
            GLL16(kg + (brow + s0 + kb + kr) * HS_ + ks8 * 8, &sK[kb][0]);
            const int vb = w * 16 + i * 8;   // sVt rows, 16 issues total
            GLL16(vt_b + (size_t)(vb + vr) * T_ + s0 + vs8 * 8, &sVt[vb][0]);
        }
        __syncthreads();

        floatx4 acc_s[4];
        #pragma unroll
        for (int c = 0; c < 4; ++c) acc_s[c] = (floatx4){0.f, 0.f, 0.f, 0.f};
        #pragma unroll
        for (int kt = 0; kt < 4; ++kt)
            #pragma unroll
            for (int c = 0; c < 4; ++c) {
                const bf16x8 bk = *(const bf16x8*)&sK[c * 16 + l16][kt * 32 + quad * 8];
                acc_s[c] = __builtin_amdgcn_mfma_f32_16x16x32_bf16(aq[kt], bk, acc_s[c], 0, 0, 0);
            }

        // fixed-base softmax: p = exp(s*scale), masked -> 0. l accumulated per lane.
        if (st >= nt - 2) {   // tiles possibly crossing the diagonal
            #pragma unroll
            for (int r = 0; r < 4; ++r) {
                const int grow = t0 + w * 16 + quad * 4 + r;
                #pragma unroll
                for (int c = 0; c < 4; ++c) {
                    const int gcol = s0 + c * 16 + l16;
                    float p = __expf(acc_s[c][r] * scale);
                    p = (gcol > grow) ? 0.f : p;
                    lsum[r] += p;
                    sP[w][quad * 4 + r][c * 16 + l16] = __float2bfloat16(p);
                }
            }
        } else {
            #pragma unroll
            for (int r = 0; r < 4; ++r)
                #pragma unroll
                for (int c = 0; c < 4; ++c) {
                    const float p = __expf(acc_s[c][r] * scale);
                    lsum[r] += p;
                    sP[w][quad * 4 + r][c * 16 + l16] = __float2bfloat16(p);
                }
        }
        // no barrier: sP is wave-private, sVt staged before this tile's barrier

        #pragma unroll
        for (int ss = 0; ss < 2; ++ss) {
            const bf16x8 ap = *(const bf16x8*)&sP[w][l16][ss * 32 + quad * 8];
            #pragma unroll
            for (int c = 0; c < 8; ++c) {
                const bf16x8 bv = *(const bf16x8*)&sVt[c * 16 + l16][ss * 32 + quad * 8];
                acc_o[c] = __builtin_amdgcn_mfma_f32_16x16x32_bf16(ap, bv, acc_o[c], 0, 0, 0);
            }
        }
        __syncthreads();   // protect sK/sVt before next stage
    }

    // epilogue: reduce l across the 16 lanes holding each row, write partials
    float lred[4];
    #pragma unroll
    for (int r = 0; r < 4; ++r) {
        float l = lsum[r];
        #pragma unroll
        for (int off = 8; off >= 1; off >>= 1) l += __shfl_xor(l, off, 64);
        lred[r] = l;
    }
    __hip_bfloat16* op = Opart + (size_t)s * M_ * HS_;
    #pragma unroll
    for (int c = 0; c < 8; ++c)
        #pragma unroll
        for (int r = 0; r < 4; ++r)
            op[(brow + t0 + w * 16 + quad * 4 + r) * HS_ + c * 16 + l16] =
                __float2bfloat16(acc_o[c][r]);
    if (l16 == 0) {
        #pragma unroll
        for (int r = 0; r < 4; ++r)
            lpart[s * M_ + brow + t0 + w * 16 + quad * 4 + r] = lred[r];
    }
}

// ---------------------------------------------------------------------------
// Merge 4 key-split partials: out = (sum O_s) / (sum l_s).
// ---------------------------------------------------------------------------
__global__ void merge(const __hip_bfloat16* __restrict__ Opart,
                      const float* __restrict__ lpart, float* __restrict__ out)
{
    const int idx = blockIdx.x * 256 + threadIdx.x;   // 262144 = 16384 rows x 16 segs
    const int row = idx >> 4;
    const int c8  = (idx & 15) * 8;
    const float l = lpart[row] + lpart[M_ + row] + lpart[2 * M_ + row] + lpart[3 * M_ + row];
    const float inv = 1.0f / l;
    float o[8] = {0.f, 0.f, 0.f, 0.f, 0.f, 0.f, 0.f, 0.f};
    #pragma unroll
    for (int sp = 0; sp < 4; ++sp) {
        const bf16x8 v = *(const bf16x8*)(Opart + (size_t)sp * M_ * HS_ + (size_t)row * HS_ + c8);
        #pragma unroll
        for (int j = 0; j < 8; ++j) o[j] += (float)v[j];
    }
    float4 ra, rb;
    ra.x = o[0] * inv; ra.y = o[1] * inv; ra.z = o[2] * inv; ra.w = o[3] * inv;
    rb.x = o[4] * inv; rb.y = o[5] * inv; rb.z = o[6] * inv; rb.w = o[7] * inv;
    *(float4*)(out + (size_t)row * HS_ + c8)     = ra;
    *(float4*)(out + (size_t)row * HS_ + c8 + 4) = rb;
}

extern "C" void kernel_launch(void* const* d_in, const int* in_sizes, int n_in,
                              void* d_out, int out_size, void* d_ws, size_t ws_size,
                              hipStream_t stream) {
    const float* x  = (const float*)d_in[0];
    const float* Wq = (const float*)d_in[1];
    const float* Wk = (const float*)d_in[2];
    const float* Wv = (const float*)d_in[3];
    char* ws = (char*)d_ws;

    __hip_bfloat16* qg  = (__hip_bfloat16*)(ws + OFF_Q);
    __hip_bfloat16* kg  = (__hip_bfloat16*)(ws + OFF_K);
    __hip_bfloat16* vtg = (__hip_bfloat16*)(ws + OFF_VT);
    __hip_bfloat16* Wt  = (__hip_bfloat16*)(ws + OFF_WT);
    __hip_bfloat16* Opart = (__hip_bfloat16*)(ws + OFF_OP);
    float* lpart = (float*)(ws + OFF_LP);

    wprep<<<dim3(16, 3), 256, 0, stream>>>(Wq, Wk, Wv, Wt);
    qkv_gemm<<<dim3(128, 3), 256, 0, stream>>>(x, Wt, qg, kg, vtg);
    attn<<<dim3(4, 16, 8), 512, 0, stream>>>(qg, kg, vtg, Opart, lpart);
    merge<<<1024, 256, 0, stream>>>(Opart, lpart, (float*)d_out);
}

// Round 4
// 173.615 us; speedup vs baseline: 1.4780x; 1.4780x over previous
//
#include <hip/hip_runtime.h>
#include <hip/hip_bf16.h>

// B=8, T=2048, D=1024, HS=128 causal attention head.
// wprep (W->Wt bf16) ; qkv_gemm (padded LDS + register double-buffer, V transposed)
// attn (fixed-base softmax, 4-way key split, 8 waves, padded LDS + reg prefetch) ; merge.

typedef __bf16 bf16x8 __attribute__((ext_vector_type(8)));
typedef __bf16 bf16x4 __attribute__((ext_vector_type(4)));
typedef float floatx4 __attribute__((ext_vector_type(4)));

#define B_  8
#define T_  2048
#define D_  1024
#define HS_ 128
#define M_  (B_ * T_)   // 16384

// ws byte offsets (end = 30408704, proven safe)
#define OFF_Q   0u
#define OFF_K   4194304u
#define OFF_VT  8388608u
#define OFF_WT  12582912u          // 3*128*1024*2 = 786432
#define OFF_OP  13369344u          // 4 splits * 16384*128*2 (bf16) = 16777216
#define OFF_LP  30146560u          // 4 * 16384 * 4 = 262144

// ---------------------------------------------------------------------------
// W[1024,128] fp32 -> Wt[128,1024] bf16 (x3), coalesced via LDS transpose.
// ---------------------------------------------------------------------------
__global__ __launch_bounds__(256) void wprep(
    const float* __restrict__ Wq, const float* __restrict__ Wk,
    const float* __restrict__ Wv, __hip_bfloat16* __restrict__ Wt)
{
    __shared__ __align__(16) __hip_bfloat16 sT[128][80];
    const int wsel = blockIdx.y;
    const int k0   = blockIdx.x * 64;
    const float* W = (wsel == 0) ? Wq : ((wsel == 1) ? Wk : Wv);

    #pragma unroll
    for (int i = 0; i < 8; ++i) {
        const int idx = threadIdx.x + i * 256;
        const int kr  = idx >> 5;
        const int f4  = idx & 31;
        const float4 v = *(const float4*)(W + (size_t)(k0 + kr) * HS_ + f4 * 4);
        sT[f4 * 4 + 0][kr] = __float2bfloat16(v.x);
        sT[f4 * 4 + 1][kr] = __float2bfloat16(v.y);
        sT[f4 * 4 + 2][kr] = __float2bfloat16(v.z);
        sT[f4 * 4 + 3][kr] = __float2bfloat16(v.w);
    }
    __syncthreads();
    #pragma unroll
    for (int i = 0; i < 4; ++i) {
        const int idx = threadIdx.x + i * 256;
        const int n   = idx >> 3;
        const int sg  = idx & 7;
        *(bf16x8*)(Wt + (size_t)wsel * HS_ * D_ + (size_t)n * D_ + k0 + sg * 8) =
            *(const bf16x8*)&sT[n][sg * 8];
    }
}

// ---------------------------------------------------------------------------
// QKV GEMM: C[16384,128] = bf16(x)*Wt^T. Tile 128x128, BK=64, padded LDS,
// register double-buffer (global loads for t+1 overlap MFMAs on t).
// grid (128, 3), 256 threads. V written transposed [b][hs][t].
// ---------------------------------------------------------------------------
__global__ __launch_bounds__(256) void qkv_gemm(
    const float* __restrict__ x, const __hip_bfloat16* __restrict__ Wt_all,
    __hip_bfloat16* __restrict__ qg, __hip_bfloat16* __restrict__ kg,
    __hip_bfloat16* __restrict__ vtg)
{
    __shared__ __align__(16) __hip_bfloat16 sA[128][72];   // stride 144B == 4 banks mod 32: <=2-way
    __shared__ __align__(16) __hip_bfloat16 sB[128][72];

    const int mt   = blockIdx.x;
    const int wsel = blockIdx.y;
    const __hip_bfloat16* Wt = Wt_all + (size_t)wsel * HS_ * D_;

    const int tid  = threadIdx.x;
    const int lane = tid & 63;
    const int w    = tid >> 6;
    const int quad = lane >> 4;
    const int l16  = lane & 15;
    const int wrow = (w & 1) * 64;
    const int wcol = (w >> 1) * 64;
    const int m0   = mt * 128;

    const int srow = tid >> 1;   // 0..127
    const int sseg = tid & 1;    // 32-col half

    floatx4 acc[4][4];
    #pragma unroll
    for (int i = 0; i < 4; ++i)
        #pragma unroll
        for (int j = 0; j < 4; ++j) acc[i][j] = (floatx4){0.f, 0.f, 0.f, 0.f};

    float4 pa[8];
    bf16x8 pb[4];
    const float* arow = x + (size_t)(m0 + srow) * D_ + sseg * 32;
    const __hip_bfloat16* browp = Wt + (size_t)srow * D_ + sseg * 32;

    // preload tile 0
    #pragma unroll
    for (int jj = 0; jj < 4; ++jj) {
        pa[2 * jj]     = *(const float4*)(arow + jj * 8);
        pa[2 * jj + 1] = *(const float4*)(arow + jj * 8 + 4);
        pb[jj]         = *(const bf16x8*)(browp + jj * 8);
    }

    for (int kt = 0; kt < D_ / 64; ++kt) {
        __syncthreads();   // prior tile's LDS reads complete
        #pragma unroll
        for (int jj = 0; jj < 4; ++jj) {
            union { bf16x8 v; __hip_bfloat16 h[8]; } u;
            u.h[0] = __float2bfloat16(pa[2 * jj].x);     u.h[1] = __float2bfloat16(pa[2 * jj].y);
            u.h[2] = __float2bfloat16(pa[2 * jj].z);     u.h[3] = __float2bfloat16(pa[2 * jj].w);
            u.h[4] = __float2bfloat16(pa[2 * jj + 1].x); u.h[5] = __float2bfloat16(pa[2 * jj + 1].y);
            u.h[6] = __float2bfloat16(pa[2 * jj + 1].z); u.h[7] = __float2bfloat16(pa[2 * jj + 1].w);
            *(bf16x8*)&sA[srow][sseg * 32 + jj * 8] = u.v;
            *(bf16x8*)&sB[srow][sseg * 32 + jj * 8] = pb[jj];
        }
        __syncthreads();

        if (kt + 1 < D_ / 64) {   // issue next tile's loads; overlap with MFMAs below
            const float* an = arow + (kt + 1) * 64;
            const __hip_bfloat16* bn = browp + (kt + 1) * 64;
            #pragma unroll
            for (int jj = 0; jj < 4; ++jj) {
                pa[2 * jj]     = *(const float4*)(an + jj * 8);
                pa[2 * jj + 1] = *(const float4*)(an + jj * 8 + 4);
                pb[jj]         = *(const bf16x8*)(bn + jj * 8);
            }
        }

        #pragma unroll
        for (int ks = 0; ks < 2; ++ks) {
            bf16x8 af[4], bfr[4];
            #pragma unroll
            for (int i = 0; i < 4; ++i)
                af[i] = *(const bf16x8*)&sA[wrow + i * 16 + l16][ks * 32 + quad * 8];
            #pragma unroll
            for (int j = 0; j < 4; ++j)
                bfr[j] = *(const bf16x8*)&sB[wcol + j * 16 + l16][ks * 32 + quad * 8];
            #pragma unroll
            for (int i = 0; i < 4; ++i)
                #pragma unroll
                for (int j = 0; j < 4; ++j)
                    acc[i][j] = __builtin_amdgcn_mfma_f32_16x16x32_bf16(af[i], bfr[j], acc[i][j], 0, 0, 0);
        }
    }

    if (wsel < 2) {
        __hip_bfloat16* out = wsel ? kg : qg;
        #pragma unroll
        for (int i = 0; i < 4; ++i)
            #pragma unroll
            for (int j = 0; j < 4; ++j)
                #pragma unroll
                for (int r = 0; r < 4; ++r)
                    out[(size_t)(m0 + wrow + i * 16 + quad * 4 + r) * HS_ + wcol + j * 16 + l16] =
                        __float2bfloat16(acc[i][j][r]);
    } else {
        #pragma unroll
        for (int i = 0; i < 4; ++i) {
            const int row0 = m0 + wrow + i * 16 + quad * 4;
            const int bb = row0 >> 11;
            const int t  = row0 & 2047;
            #pragma unroll
            for (int j = 0; j < 4; ++j) {
                const int col = wcol + j * 16 + l16;
                union { bf16x4 v; __hip_bfloat16 h[4]; } u;
                #pragma unroll
                for (int r = 0; r < 4; ++r) u.h[r] = __float2bfloat16(acc[i][j][r]);
                *(bf16x4*)(vtg + (size_t)bb * HS_ * T_ + (size_t)col * T_ + t) = u.v;
            }
        }
    }
}

// ---------------------------------------------------------------------------
// Flash attention, fixed-base softmax. grid (4 split, 16 qt rev, 8 b),
// 512 threads = 8 waves, 128 q-rows/block. Padded LDS, register prefetch.
// ---------------------------------------------------------------------------
__global__ __launch_bounds__(512) void attn(
    const __hip_bfloat16* __restrict__ qg, const __hip_bfloat16* __restrict__ kg,
    const __hip_bfloat16* __restrict__ vtg,
    __hip_bfloat16* __restrict__ Opart, float* __restrict__ lpart)
{
    __shared__ __align__(16) __hip_bfloat16 sK[64][136];   // 272B stride: <=2-way
    __shared__ __align__(16) __hip_bfloat16 sVt[128][72];
    __shared__ __align__(16) __hip_bfloat16 sP[8][16][72];

    const int s  = blockIdx.x;
    const int qt = 15 - blockIdx.y;
    const int b  = blockIdx.z;

    const int tid  = threadIdx.x;
    const int lane = tid & 63;
    const int w    = tid >> 6;
    const int quad = lane >> 4;
    const int l16  = lane & 15;

    const int t0 = qt * 128;
    const size_t brow = (size_t)b * T_;
    const __hip_bfloat16* vt_b = vtg + (size_t)b * HS_ * T_;

    const int nt = 2 * qt + 2;
    const int st_begin = (s * nt) >> 2;
    const int st_end   = ((s + 1) * nt) >> 2;

    bf16x8 aq[4];
    #pragma unroll
    for (int kt = 0; kt < 4; ++kt)
        aq[kt] = *(const bf16x8*)(qg + (brow + t0 + w * 16 + l16) * HS_ + kt * 32 + quad * 8);

    floatx4 acc_o[8];
    #pragma unroll
    for (int i = 0; i < 8; ++i) acc_o[i] = (floatx4){0.f, 0.f, 0.f, 0.f};
    float lsum[4] = {0.f, 0.f, 0.f, 0.f};

    const float scale = 0.08838834764831845f;

    // staging assignments (2 issues each for K and Vt)
    const int kr0 = tid >> 4,           ksg = tid & 15;   // K: idx<512 -> rows 0..31
    const int vr0 = tid >> 3,           vsg = tid & 7;    // Vt: idx<512 -> rows 0..63

    bf16x8 pk[2], pv[2];
    if (st_begin < st_end) {
        const int s0 = st_begin * 64;
        pk[0] = *(const bf16x8*)(kg + (brow + s0 + kr0) * HS_ + ksg * 8);
        pk[1] = *(const bf16x8*)(kg + (brow + s0 + kr0 + 32) * HS_ + ksg * 8);
        pv[0] = *(const bf16x8*)(vt_b + (size_t)vr0 * T_ + s0 + vsg * 8);
        pv[1] = *(const bf16x8*)(vt_b + (size_t)(vr0 + 64) * T_ + s0 + vsg * 8);
    }

    for (int st = st_begin; st < st_end; ++st) {
        const int s0 = st * 64;
        __syncthreads();   // prior tile's LDS reads done
        *(bf16x8*)&sK[kr0][ksg * 8]      = pk[0];
        *(bf16x8*)&sK[kr0 + 32][ksg * 8] = pk[1];
        *(bf16x8*)&sVt[vr0][vsg * 8]      = pv[0];
        *(bf16x8*)&sVt[vr0 + 64][vsg * 8] = pv[1];
        __syncthreads();

        if (st + 1 < st_end) {   // prefetch next tile; overlaps compute below
            const int s1 = s0 + 64;
            pk[0] = *(const bf16x8*)(kg + (brow + s1 + kr0) * HS_ + ksg * 8);
            pk[1] = *(const bf16x8*)(kg + (brow + s1 + kr0 + 32) * HS_ + ksg * 8);
            pv[0] = *(const bf16x8*)(vt_b + (size_t)vr0 * T_ + s1 + vsg * 8);
            pv[1] = *(const bf16x8*)(vt_b + (size_t)(vr0 + 64) * T_ + s1 + vsg * 8);
        }

        floatx4 acc_s[4];
        #pragma unroll
        for (int c = 0; c < 4; ++c) acc_s[c] = (floatx4){0.f, 0.f, 0.f, 0.f};
        #pragma unroll
        for (int kt = 0; kt < 4; ++kt)
            #pragma unroll
            for (int c = 0; c < 4; ++c) {
                const bf16x8 bk = *(const bf16x8*)&sK[c * 16 + l16][kt * 32 + quad * 8];
                acc_s[c] = __builtin_amdgcn_mfma_f32_16x16x32_bf16(aq[kt], bk, acc_s[c], 0, 0, 0);
            }

        if (st >= nt - 2) {   // tiles possibly crossing the diagonal
            #pragma unroll
            for (int r = 0; r < 4; ++r) {
                const int grow = t0 + w * 16 + quad * 4 + r;
                #pragma unroll
                for (int c = 0; c < 4; ++c) {
                    const int gcol = s0 + c * 16 + l16;
                    float p = __expf(acc_s[c][r] * scale);
                    p = (gcol > grow) ? 0.f : p;
                    lsum[r] += p;
                    sP[w][quad * 4 + r][c * 16 + l16] = __float2bfloat16(p);
                }
            }
        } else {
            #pragma unroll
            for (int r = 0; r < 4; ++r)
                #pragma unroll
                for (int c = 0; c < 4; ++c) {
                    const float p = __expf(acc_s[c][r] * scale);
                    lsum[r] += p;
                    sP[w][quad * 4 + r][c * 16 + l16] = __float2bfloat16(p);
                }
        }
        // sP is wave-private: no barrier needed before PV

        #pragma unroll
        for (int ss = 0; ss < 2; ++ss) {
            const bf16x8 ap = *(const bf16x8*)&sP[w][l16][ss * 32 + quad * 8];
            #pragma unroll
            for (int c = 0; c < 8; ++c) {
                const bf16x8 bv = *(const bf16x8*)&sVt[c * 16 + l16][ss * 32 + quad * 8];
                acc_o[c] = __builtin_amdgcn_mfma_f32_16x16x32_bf16(ap, bv, acc_o[c], 0, 0, 0);
            }
        }
    }

    float lred[4];
    #pragma unroll
    for (int r = 0; r < 4; ++r) {
        float l = lsum[r];
        #pragma unroll
        for (int off = 8; off >= 1; off >>= 1) l += __shfl_xor(l, off, 64);
        lred[r] = l;
    }
    __hip_bfloat16* op = Opart + (size_t)s * M_ * HS_;
    #pragma unroll
    for (int c = 0; c < 8; ++c)
        #pragma unroll
        for (int r = 0; r < 4; ++r)
            op[(brow + t0 + w * 16 + quad * 4 + r) * HS_ + c * 16 + l16] =
                __float2bfloat16(acc_o[c][r]);
    if (l16 == 0) {
        #pragma unroll
        for (int r = 0; r < 4; ++r)
            lpart[s * M_ + brow + t0 + w * 16 + quad * 4 + r] = lred[r];
    }
}

// ---------------------------------------------------------------------------
// Merge 4 key-split partials: out = (sum O_s) / (sum l_s).
// ---------------------------------------------------------------------------
__global__ void merge(const __hip_bfloat16* __restrict__ Opart,
                      const float* __restrict__ lpart, float* __restrict__ out)
{
    const int idx = blockIdx.x * 256 + threadIdx.x;
    const int row = idx >> 4;
    const int c8  = (idx & 15) * 8;
    const float l = lpart[row] + lpart[M_ + row] + lpart[2 * M_ + row] + lpart[3 * M_ + row];
    const float inv = 1.0f / l;
    float o[8] = {0.f, 0.f, 0.f, 0.f, 0.f, 0.f, 0.f, 0.f};
    #pragma unroll
    for (int sp = 0; sp < 4; ++sp) {
        const bf16x8 v = *(const bf16x8*)(Opart + (size_t)sp * M_ * HS_ + (size_t)row * HS_ + c8);
        #pragma unroll
        for (int j = 0; j < 8; ++j) o[j] += (float)v[j];
    }
    float4 ra, rb;
    ra.x = o[0] * inv; ra.y = o[1] * inv; ra.z = o[2] * inv; ra.w = o[3] * inv;
    rb.x = o[4] * inv; rb.y = o[5] * inv; rb.z = o[6] * inv; rb.w = o[7] * inv;
    *(float4*)(out + (size_t)row * HS_ + c8)     = ra;
    *(float4*)(out + (size_t)row * HS_ + c8 + 4) = rb;
}

extern "C" void kernel_launch(void* const* d_in, const int* in_sizes, int n_in,
                              void* d_out, int out_size, void* d_ws, size_t ws_size,
                              hipStream_t stream) {
    const float* x  = (const float*)d_in[0];
    const float* Wq = (const float*)d_in[1];
    const float* Wk = (const float*)d_in[2];
    const float* Wv = (const float*)d_in[3];
    char* ws = (char*)d_ws;

    __hip_bfloat16* qg  = (__hip_bfloat16*)(ws + OFF_Q);
    __hip_bfloat16* kg  = (__hip_bfloat16*)(ws + OFF_K);
    __hip_bfloat16* vtg = (__hip_bfloat16*)(ws + OFF_VT);
    __hip_bfloat16* Wt  = (__hip_bfloat16*)(ws + OFF_WT);
    __hip_bfloat16* Opart = (__hip_bfloat16*)(ws + OFF_OP);
    float* lpart = (float*)(ws + OFF_LP);

    wprep<<<dim3(16, 3), 256, 0, stream>>>(Wq, Wk, Wv, Wt);
    qkv_gemm<<<dim3(128, 3), 256, 0, stream>>>(x, Wt, qg, kg, vtg);
    attn<<<dim3(4, 16, 8), 512, 0, stream>>>(qg, kg, vtg, Opart, lpart);
    merge<<<1024, 256, 0, stream>>>(Opart, lpart, (float*)d_out);
}

// Round 5
// 160.564 us; speedup vs baseline: 1.5982x; 1.0813x over previous
//
#include <hip/hip_runtime.h>
#include <hip/hip_bf16.h>

// B=8, T=2048, D=1024, HS=128 causal attention head.
// wprep (W->Wt bf16) ; qkv_gemm (64x128 tile, grid 768, padded LDS + reg dbuf, V transposed)
// attn (fixed-base softmax, 4-way key split, 8 waves, padded LDS + reg prefetch) ; merge.

typedef __bf16 bf16x8 __attribute__((ext_vector_type(8)));
typedef __bf16 bf16x4 __attribute__((ext_vector_type(4)));
typedef float floatx4 __attribute__((ext_vector_type(4)));

#define B_  8
#define T_  2048
#define D_  1024
#define HS_ 128
#define M_  (B_ * T_)   // 16384

// ws byte offsets (end = 30408704, proven safe)
#define OFF_Q   0u
#define OFF_K   4194304u
#define OFF_VT  8388608u
#define OFF_WT  12582912u          // 3*128*1024*2 = 786432
#define OFF_OP  13369344u          // 4 splits * 16384*128*2 (bf16) = 16777216
#define OFF_LP  30146560u          // 4 * 16384 * 4 = 262144

// ---------------------------------------------------------------------------
// W[1024,128] fp32 -> Wt[128,1024] bf16 (x3), coalesced via LDS transpose.
// ---------------------------------------------------------------------------
__global__ __launch_bounds__(256) void wprep(
    const float* __restrict__ Wq, const float* __restrict__ Wk,
    const float* __restrict__ Wv, __hip_bfloat16* __restrict__ Wt)
{
    __shared__ __align__(16) __hip_bfloat16 sT[128][80];
    const int wsel = blockIdx.y;
    const int k0   = blockIdx.x * 64;
    const float* W = (wsel == 0) ? Wq : ((wsel == 1) ? Wk : Wv);

    #pragma unroll
    for (int i = 0; i < 8; ++i) {
        const int idx = threadIdx.x + i * 256;
        const int kr  = idx >> 5;
        const int f4  = idx & 31;
        const float4 v = *(const float4*)(W + (size_t)(k0 + kr) * HS_ + f4 * 4);
        sT[f4 * 4 + 0][kr] = __float2bfloat16(v.x);
        sT[f4 * 4 + 1][kr] = __float2bfloat16(v.y);
        sT[f4 * 4 + 2][kr] = __float2bfloat16(v.z);
        sT[f4 * 4 + 3][kr] = __float2bfloat16(v.w);
    }
    __syncthreads();
    #pragma unroll
    for (int i = 0; i < 4; ++i) {
        const int idx = threadIdx.x + i * 256;
        const int n   = idx >> 3;
        const int sg  = idx & 7;
        *(bf16x8*)(Wt + (size_t)wsel * HS_ * D_ + (size_t)n * D_ + k0 + sg * 8) =
            *(const bf16x8*)&sT[n][sg * 8];
    }
}

// ---------------------------------------------------------------------------
// QKV GEMM: C[16384,128] = bf16(x)*Wt^T. Tile 64x128, BK=64, grid (256,3)=768
// blocks (3/CU). Padded LDS, register double-buffer. V written transposed.
// Waves: 2x2, each 32 rows x 64 cols (2x4 MFMA micro-tile).
// ---------------------------------------------------------------------------
__global__ __launch_bounds__(256) void qkv_gemm(
    const float* __restrict__ x, const __hip_bfloat16* __restrict__ Wt_all,
    __hip_bfloat16* __restrict__ qg, __hip_bfloat16* __restrict__ kg,
    __hip_bfloat16* __restrict__ vtg)
{
    __shared__ __align__(16) __hip_bfloat16 sA[64][72];    // stride 144B: <=2-way banks
    __shared__ __align__(16) __hip_bfloat16 sB[128][72];

    const int mt   = blockIdx.x;
    const int wsel = blockIdx.y;
    const __hip_bfloat16* Wt = Wt_all + (size_t)wsel * HS_ * D_;

    const int tid  = threadIdx.x;
    const int lane = tid & 63;
    const int w    = tid >> 6;
    const int quad = lane >> 4;
    const int l16  = lane & 15;
    const int wrow = (w & 1) * 32;
    const int wcol = (w >> 1) * 64;
    const int m0   = mt * 64;

    const int srA = tid >> 2, scA = (tid & 3) * 16;   // A: 64 rows, 16 cols/thread
    const int srB = tid >> 1, scB = (tid & 1) * 32;   // B: 128 rows, 32 cols/thread

    floatx4 acc[2][4];
    #pragma unroll
    for (int i = 0; i < 2; ++i)
        #pragma unroll
        for (int j = 0; j < 4; ++j) acc[i][j] = (floatx4){0.f, 0.f, 0.f, 0.f};

    float4 pa[4];
    bf16x8 pb[4];
    const float* arow = x + (size_t)(m0 + srA) * D_ + scA;
    const __hip_bfloat16* browp = Wt + (size_t)srB * D_ + scB;

    // preload tile 0
    #pragma unroll
    for (int jj = 0; jj < 4; ++jj) {
        pa[jj] = *(const float4*)(arow + jj * 4);
        pb[jj] = *(const bf16x8*)(browp + jj * 8);
    }

    for (int kt = 0; kt < D_ / 64; ++kt) {
        __syncthreads();   // prior tile's LDS reads complete
        {
            union { bf16x8 v; __hip_bfloat16 h[8]; } u0, u1;
            u0.h[0] = __float2bfloat16(pa[0].x); u0.h[1] = __float2bfloat16(pa[0].y);
            u0.h[2] = __float2bfloat16(pa[0].z); u0.h[3] = __float2bfloat16(pa[0].w);
            u0.h[4] = __float2bfloat16(pa[1].x); u0.h[5] = __float2bfloat16(pa[1].y);
            u0.h[6] = __float2bfloat16(pa[1].z); u0.h[7] = __float2bfloat16(pa[1].w);
            u1.h[0] = __float2bfloat16(pa[2].x); u1.h[1] = __float2bfloat16(pa[2].y);
            u1.h[2] = __float2bfloat16(pa[2].z); u1.h[3] = __float2bfloat16(pa[2].w);
            u1.h[4] = __float2bfloat16(pa[3].x); u1.h[5] = __float2bfloat16(pa[3].y);
            u1.h[6] = __float2bfloat16(pa[3].z); u1.h[7] = __float2bfloat16(pa[3].w);
            *(bf16x8*)&sA[srA][scA]     = u0.v;
            *(bf16x8*)&sA[srA][scA + 8] = u1.v;
            #pragma unroll
            for (int jj = 0; jj < 4; ++jj)
                *(bf16x8*)&sB[srB][scB + jj * 8] = pb[jj];
        }
        __syncthreads();

        if (kt + 1 < D_ / 64) {   // next tile's global loads overlap MFMAs below
            const float* an = arow + (kt + 1) * 64;
            const __hip_bfloat16* bn = browp + (kt + 1) * 64;
            #pragma unroll
            for (int jj = 0; jj < 4; ++jj) {
                pa[jj] = *(const float4*)(an + jj * 4);
                pb[jj] = *(const bf16x8*)(bn + jj * 8);
            }
        }

        #pragma unroll
        for (int ks = 0; ks < 2; ++ks) {
            bf16x8 af[2], bfr[4];
            #pragma unroll
            for (int i = 0; i < 2; ++i)
                af[i] = *(const bf16x8*)&sA[wrow + i * 16 + l16][ks * 32 + quad * 8];
            #pragma unroll
            for (int j = 0; j < 4; ++j)
                bfr[j] = *(const bf16x8*)&sB[wcol + j * 16 + l16][ks * 32 + quad * 8];
            #pragma unroll
            for (int i = 0; i < 2; ++i)
                #pragma unroll
                for (int j = 0; j < 4; ++j)
                    acc[i][j] = __builtin_amdgcn_mfma_f32_16x16x32_bf16(af[i], bfr[j], acc[i][j], 0, 0, 0);
        }
    }

    if (wsel < 2) {
        __hip_bfloat16* out = wsel ? kg : qg;
        #pragma unroll
        for (int i = 0; i < 2; ++i)
            #pragma unroll
            for (int j = 0; j < 4; ++j)
                #pragma unroll
                for (int r = 0; r < 4; ++r)
                    out[(size_t)(m0 + wrow + i * 16 + quad * 4 + r) * HS_ + wcol + j * 16 + l16] =
                        __float2bfloat16(acc[i][j][r]);
    } else {
        #pragma unroll
        for (int i = 0; i < 2; ++i) {
            const int row0 = m0 + wrow + i * 16 + quad * 4;
            const int bb = row0 >> 11;
            const int t  = row0 & 2047;
            #pragma unroll
            for (int j = 0; j < 4; ++j) {
                const int col = wcol + j * 16 + l16;
                union { bf16x4 v; __hip_bfloat16 h[4]; } u;
                #pragma unroll
                for (int r = 0; r < 4; ++r) u.h[r] = __float2bfloat16(acc[i][j][r]);
                *(bf16x4*)(vtg + (size_t)bb * HS_ * T_ + (size_t)col * T_ + t) = u.v;
            }
        }
    }
}

// ---------------------------------------------------------------------------
// Flash attention, fixed-base softmax. grid (4 split, 16 qt rev, 8 b),
// 512 threads = 8 waves, 128 q-rows/block. Padded LDS, register prefetch.
// ---------------------------------------------------------------------------
__global__ __launch_bounds__(512) void attn(
    const __hip_bfloat16* __restrict__ qg, const __hip_bfloat16* __restrict__ kg,
    const __hip_bfloat16* __restrict__ vtg,
    __hip_bfloat16* __restrict__ Opart, float* __restrict__ lpart)
{
    __shared__ __align__(16) __hip_bfloat16 sK[64][136];   // 272B stride: <=2-way
    __shared__ __align__(16) __hip_bfloat16 sVt[128][72];
    __shared__ __align__(16) __hip_bfloat16 sP[8][16][72];

    const int s  = blockIdx.x;
    const int qt = 15 - blockIdx.y;
    const int b  = blockIdx.z;

    const int tid  = threadIdx.x;
    const int lane = tid & 63;
    const int w    = tid >> 6;
    const int quad = lane >> 4;
    const int l16  = lane & 15;

    const int t0 = qt * 128;
    const size_t brow = (size_t)b * T_;
    const __hip_bfloat16* vt_b = vtg + (size_t)b * HS_ * T_;

    const int nt = 2 * qt + 2;
    const int st_begin = (s * nt) >> 2;
    const int st_end   = ((s + 1) * nt) >> 2;

    bf16x8 aq[4];
    #pragma unroll
    for (int kt = 0; kt < 4; ++kt)
        aq[kt] = *(const bf16x8*)(qg + (brow + t0 + w * 16 + l16) * HS_ + kt * 32 + quad * 8);

    floatx4 acc_o[8];
    #pragma unroll
    for (int i = 0; i < 8; ++i) acc_o[i] = (floatx4){0.f, 0.f, 0.f, 0.f};
    float lsum[4] = {0.f, 0.f, 0.f, 0.f};

    const float scale = 0.08838834764831845f;

    const int kr0 = tid >> 4, ksg = tid & 15;
    const int vr0 = tid >> 3, vsg = tid & 7;

    bf16x8 pk[2], pv[2];
    if (st_begin < st_end) {
        const int s0 = st_begin * 64;
        pk[0] = *(const bf16x8*)(kg + (brow + s0 + kr0) * HS_ + ksg * 8);
        pk[1] = *(const bf16x8*)(kg + (brow + s0 + kr0 + 32) * HS_ + ksg * 8);
        pv[0] = *(const bf16x8*)(vt_b + (size_t)vr0 * T_ + s0 + vsg * 8);
        pv[1] = *(const bf16x8*)(vt_b + (size_t)(vr0 + 64) * T_ + s0 + vsg * 8);
    }

    for (int st = st_begin; st < st_end; ++st) {
        const int s0 = st * 64;
        __syncthreads();
        *(bf16x8*)&sK[kr0][ksg * 8]      = pk[0];
        *(bf16x8*)&sK[kr0 + 32][ksg * 8] = pk[1];
        *(bf16x8*)&sVt[vr0][vsg * 8]      = pv[0];
        *(bf16x8*)&sVt[vr0 + 64][vsg * 8] = pv[1];
        __syncthreads();

        if (st + 1 < st_end) {
            const int s1 = s0 + 64;
            pk[0] = *(const bf16x8*)(kg + (brow + s1 + kr0) * HS_ + ksg * 8);
            pk[1] = *(const bf16x8*)(kg + (brow + s1 + kr0 + 32) * HS_ + ksg * 8);
            pv[0] = *(const bf16x8*)(vt_b + (size_t)vr0 * T_ + s1 + vsg * 8);
            pv[1] = *(const bf16x8*)(vt_b + (size_t)(vr0 + 64) * T_ + s1 + vsg * 8);
        }

        floatx4 acc_s[4];
        #pragma unroll
        for (int c = 0; c < 4; ++c) acc_s[c] = (floatx4){0.f, 0.f, 0.f, 0.f};
        #pragma unroll
        for (int kt = 0; kt < 4; ++kt)
            #pragma unroll
            for (int c = 0; c < 4; ++c) {
                const bf16x8 bk = *(const bf16x8*)&sK[c * 16 + l16][kt * 32 + quad * 8];
                acc_s[c] = __builtin_amdgcn_mfma_f32_16x16x32_bf16(aq[kt], bk, acc_s[c], 0, 0, 0);
            }

        if (st >= nt - 2) {
            #pragma unroll
            for (int r = 0; r < 4; ++r) {
                const int grow = t0 + w * 16 + quad * 4 + r;
                #pragma unroll
                for (int c = 0; c < 4; ++c) {
                    const int gcol = s0 + c * 16 + l16;
                    float p = __expf(acc_s[c][r] * scale);
                    p = (gcol > grow) ? 0.f : p;
                    lsum[r] += p;
                    sP[w][quad * 4 + r][c * 16 + l16] = __float2bfloat16(p);
                }
            }
        } else {
            #pragma unroll
            for (int r = 0; r < 4; ++r)
                #pragma unroll
                for (int c = 0; c < 4; ++c) {
                    const float p = __expf(acc_s[c][r] * scale);
                    lsum[r] += p;
                    sP[w][quad * 4 + r][c * 16 + l16] = __float2bfloat16(p);
                }
        }

        #pragma unroll
        for (int ss = 0; ss < 2; ++ss) {
            const bf16x8 ap = *(const bf16x8*)&sP[w][l16][ss * 32 + quad * 8];
            #pragma unroll
            for (int c = 0; c < 8; ++c) {
                const bf16x8 bv = *(const bf16x8*)&sVt[c * 16 + l16][ss * 32 + quad * 8];
                acc_o[c] = __builtin_amdgcn_mfma_f32_16x16x32_bf16(ap, bv, acc_o[c], 0, 0, 0);
            }
        }
    }

    float lred[4];
    #pragma unroll
    for (int r = 0; r < 4; ++r) {
        float l = lsum[r];
        #pragma unroll
        for (int off = 8; off >= 1; off >>= 1) l += __shfl_xor(l, off, 64);
        lred[r] = l;
    }
    __hip_bfloat16* op = Opart + (size_t)s * M_ * HS_;
    #pragma unroll
    for (int c = 0; c < 8; ++c)
        #pragma unroll
        for (int r = 0; r < 4; ++r)
            op[(brow + t0 + w * 16 + quad * 4 + r) * HS_ + c * 16 + l16] =
                __float2bfloat16(acc_o[c][r]);
    if (l16 == 0) {
        #pragma unroll
        for (int r = 0; r < 4; ++r)
            lpart[s * M_ + brow + t0 + w * 16 + quad * 4 + r] = lred[r];
    }
}

// ---------------------------------------------------------------------------
// Merge 4 key-split partials: out = (sum O_s) / (sum l_s).
// ---------------------------------------------------------------------------
__global__ void merge(const __hip_bfloat16* __restrict__ Opart,
                      const float* __restrict__ lpart, float* __restrict__ out)
{
    const int idx = blockIdx.x * 256 + threadIdx.x;
    const int row = idx >> 4;
    const int c8  = (idx & 15) * 8;
    const float l = lpart[row] + lpart[M_ + row] + lpart[2 * M_ + row] + lpart[3 * M_ + row];
    const float inv = 1.0f / l;
    float o[8] = {0.f, 0.f, 0.f, 0.f, 0.f, 0.f, 0.f, 0.f};
    #pragma unroll
    for (int sp = 0; sp < 4; ++sp) {
        const bf16x8 v = *(const bf16x8*)(Opart + (size_t)sp * M_ * HS_ + (size_t)row * HS_ + c8);
        #pragma unroll
        for (int j = 0; j < 8; ++j) o[j] += (float)v[j];
    }
    float4 ra, rb;
    ra.x = o[0] * inv; ra.y = o[1] * inv; ra.z = o[2] * inv; ra.w = o[3] * inv;
    rb.x = o[4] * inv; rb.y = o[5] * inv; rb.z = o[6] * inv; rb.w = o[7] * inv;
    *(float4*)(out + (size_t)row * HS_ + c8)     = ra;
    *(float4*)(out + (size_t)row * HS_ + c8 + 4) = rb;
}

extern "C" void kernel_launch(void* const* d_in, const int* in_sizes, int n_in,
                              void* d_out, int out_size, void* d_ws, size_t ws_size,
                              hipStream_t stream) {
    const float* x  = (const float*)d_in[0];
    const float* Wq = (const float*)d_in[1];
    const float* Wk = (const float*)d_in[2];
    const float* Wv = (const float*)d_in[3];
    char* ws = (char*)d_ws;

    __hip_bfloat16* qg  = (__hip_bfloat16*)(ws + OFF_Q);
    __hip_bfloat16* kg  = (__hip_bfloat16*)(ws + OFF_K);
    __hip_bfloat16* vtg = (__hip_bfloat16*)(ws + OFF_VT);
    __hip_bfloat16* Wt  = (__hip_bfloat16*)(ws + OFF_WT);
    __hip_bfloat16* Opart = (__hip_bfloat16*)(ws + OFF_OP);
    float* lpart = (float*)(ws + OFF_LP);

    wprep<<<dim3(16, 3), 256, 0, stream>>>(Wq, Wk, Wv, Wt);
    qkv_gemm<<<dim3(256, 3), 256, 0, stream>>>(x, Wt, qg, kg, vtg);
    attn<<<dim3(4, 16, 8), 512, 0, stream>>>(qg, kg, vtg, Opart, lpart);
    merge<<<1024, 256, 0, stream>>>(Opart, lpart, (float*)d_out);
}